// Round 3
// baseline (518.628 us; speedup 1.0000x reference)
//
#include <hip/hip_runtime.h>

#define RELU(v) fmaxf((v), 0.0f)

__device__ __forceinline__ float4 f4add(float4 a, float4 b) {
  return make_float4(a.x + b.x, a.y + b.y, a.z + b.z, a.w + b.w);
}
__device__ __forceinline__ float4 f4fma(float s, float4 w, float4 a) {
  return make_float4(fmaf(s, w.x, a.x), fmaf(s, w.y, a.y),
                     fmaf(s, w.z, a.z), fmaf(s, w.w, a.w));
}
__device__ __forceinline__ float4 f4shfl_xor_add(float4 v, int m) {
  v.x += __shfl_xor(v.x, m);
  v.y += __shfl_xor(v.y, m);
  v.z += __shfl_xor(v.z, m);
  v.w += __shfl_xor(v.w, m);
  return v;
}

// ---------- CSR build ----------

__global__ __launch_bounds__(256) void k_zero_int(int* __restrict__ p, int n) {
  int i = blockIdx.x * 256 + threadIdx.x;
  if (i < n) p[i] = 0;
}

__global__ __launch_bounds__(256) void k_hist(const int* __restrict__ dst,
                                              int* __restrict__ cnt, int ne) {
  int e = blockIdx.x * 256 + threadIdx.x;
  if (e < ne) atomicAdd(&cnt[dst[e]], 1);
}

__global__ __launch_bounds__(256) void k_blocksum(const int* __restrict__ cnt,
                                                  int* __restrict__ bsum, int n) {
  __shared__ int red[256];
  int t = threadIdx.x;
  int base = blockIdx.x * 1024;
  int s = 0;
#pragma unroll
  for (int j = 0; j < 4; ++j) {
    int idx = base + t * 4 + j;
    if (idx < n) s += cnt[idx];
  }
  red[t] = s;
  __syncthreads();
  for (int off = 128; off; off >>= 1) {
    if (t < off) red[t] += red[t + off];
    __syncthreads();
  }
  if (t == 0) bsum[blockIdx.x] = red[0];
}

__global__ void k_scan_small(const int* __restrict__ bsum,
                             int* __restrict__ boff, int nblk) {
  if (threadIdx.x == 0 && blockIdx.x == 0) {
    int run = 0;
    for (int i = 0; i < nblk; ++i) {
      int v = bsum[i];
      boff[i] = run;
      run += v;
    }
  }
}

__global__ __launch_bounds__(256) void k_scan_local(
    const int* __restrict__ cnt, const int* __restrict__ boff,
    int* __restrict__ row_start, int* __restrict__ cursor, int n) {
  __shared__ int tsum[256];
  int t = threadIdx.x;
  int base = blockIdx.x * 1024;
  int v[4];
  int s = 0;
#pragma unroll
  for (int j = 0; j < 4; ++j) {
    int idx = base + t * 4 + j;
    v[j] = (idx < n) ? cnt[idx] : 0;
    s += v[j];
  }
  tsum[t] = s;
  int x = s;
  __syncthreads();
  for (int off = 1; off < 256; off <<= 1) {
    int y = (t >= off) ? tsum[t - off] : 0;
    __syncthreads();
    x += y;
    tsum[t] = x;
    __syncthreads();
  }
  int run = boff[blockIdx.x] + x - s;
#pragma unroll
  for (int j = 0; j < 4; ++j) {
    int idx = base + t * 4 + j;
    if (idx < n) {
      row_start[idx] = run;
      cursor[idx] = run;
      run += v[j];
    }
  }
}

__global__ __launch_bounds__(256) void k_fill(const int* __restrict__ src,
                                              const int* __restrict__ dst,
                                              int* __restrict__ cursor,
                                              int* __restrict__ csr, int ne) {
  int e = blockIdx.x * 256 + threadIdx.x;
  if (e < ne) {
    int pos = atomicAdd(&cursor[dst[e]], 1);
    csr[pos] = src[e];
  }
}

__global__ __launch_bounds__(256) void k_dinv(const int* __restrict__ cnt,
                                              float* __restrict__ dinv, int n) {
  int i = blockIdx.x * 256 + threadIdx.x;
  if (i < n) dinv[i] = rsqrtf((float)(cnt[i] + 1));  // +1 self-loop
}

// ---------- dense passes ----------
// Wave layout everywhere below: one ROW (node) per wave; g = lane>>4 picks a
// 16-wide k-slice (GEMM) / edge subgroup (gather); q = lane&15 picks 4 output
// channels handled as float4. Cross-g combine: shfl_xor 16 then 32.

// tt[row][:] = dinv[row] * (x[row] @ W)
__global__ __launch_bounds__(512) void k_transform(
    const float* __restrict__ x, const float* __restrict__ W,
    const float* __restrict__ dinv, float* __restrict__ tt, int n) {
  __shared__ float Ws[64 * 64];
  __shared__ float xs[8][64];
  for (int i = threadIdx.x; i < 64 * 64; i += 512) Ws[i] = W[i];
  const int lane = threadIdx.x & 63;
  const int w = threadIdx.x >> 6;
  const int g = lane >> 4, q = lane & 15;
  const int row = blockIdx.x * 8 + w;
  const bool valid = row < n;
  if (valid) xs[w][lane] = x[(size_t)row * 64 + lane];
  __syncthreads();  // Ws ready (xs is wave-private, in-order)
  float4 o = make_float4(0.f, 0.f, 0.f, 0.f);
  const float4* Ws4 = (const float4*)Ws;
  if (valid) {
#pragma unroll
    for (int i = 0; i < 16; ++i) {
      int k = g * 16 + i;
      o = f4fma(xs[w][k], Ws4[k * 16 + q], o);
    }
  }
  o = f4shfl_xor_add(o, 16);
  o = f4shfl_xor_add(o, 32);
  if (valid && g == 0) {
    float di = dinv[row];
    ((float4*)tt)[(size_t)row * 16 + q] =
        make_float4(o.x * di, o.y * di, o.z * di, o.w * di);
  }
}

// h = relu(dinv*(tt_self + sum_in tt[src]) + b); ttout = dinv * (h @ W)
__global__ __launch_bounds__(512) void k_mid_g(
    const float* __restrict__ tt, const int* __restrict__ csr,
    const int* __restrict__ row_start, const int* __restrict__ cnt,
    const float* __restrict__ dinv, const float* __restrict__ b,
    const float* __restrict__ W, float* __restrict__ ttout, int n) {
  __shared__ float Ws[64 * 64];
  __shared__ float hs[8][64];
  for (int i = threadIdx.x; i < 64 * 64; i += 512) Ws[i] = W[i];
  const int lane = threadIdx.x & 63;
  const int w = threadIdx.x >> 6;
  const int g = lane >> 4, q = lane & 15;
  const int row = blockIdx.x * 8 + w;
  const bool valid = row < n;
  const float4* tt4 = (const float4*)tt;
  float4 acc = make_float4(0.f, 0.f, 0.f, 0.f);
  float di = 0.f;
  if (valid) {
    di = dinv[row];
    if (g == 0) acc = tt4[(size_t)row * 16 + q];  // self-loop term
    int j = row_start[row] + g;
    const int jend = row_start[row] + cnt[row];
    for (; j + 4 < jend; j += 8) {  // 2 edges per subgroup in flight
      int s0 = csr[j], s1 = csr[j + 4];
      float4 v0 = tt4[(size_t)s0 * 16 + q];
      float4 v1 = tt4[(size_t)s1 * 16 + q];
      acc = f4add(acc, f4add(v0, v1));
    }
    if (j < jend) acc = f4add(acc, tt4[(size_t)csr[j] * 16 + q]);
  }
  acc = f4shfl_xor_add(acc, 16);
  acc = f4shfl_xor_add(acc, 32);
  float4 b4 = ((const float4*)b)[q];
  float4 h = make_float4(RELU(di * acc.x + b4.x), RELU(di * acc.y + b4.y),
                         RELU(di * acc.z + b4.z), RELU(di * acc.w + b4.w));
  __syncthreads();  // Ws ready
  if (valid && g == 0) ((float4*)hs[w])[q] = h;
  float4 o = make_float4(0.f, 0.f, 0.f, 0.f);
  const float4* Ws4 = (const float4*)Ws;
  if (valid) {
#pragma unroll
    for (int i = 0; i < 16; ++i) {
      int k = g * 16 + i;
      o = f4fma(hs[w][k], Ws4[k * 16 + q], o);
    }
  }
  o = f4shfl_xor_add(o, 16);
  o = f4shfl_xor_add(o, 32);
  if (valid && g == 0)
    ((float4*)ttout)[(size_t)row * 16 + q] =
        make_float4(o.x * di, o.y * di, o.z * di, o.w * di);
}

// h2 = relu(dinv*(agg)+b2); h3 = relu(h2@Wf1+bf1); h4 = relu(h3@Wf2+bf2);
// out = h4 . Wf3 + bf3
__global__ __launch_bounds__(512) void k_final_g(
    const float* __restrict__ tt, const int* __restrict__ csr,
    const int* __restrict__ row_start, const int* __restrict__ cnt,
    const float* __restrict__ dinv, const float* __restrict__ b2,
    const float* __restrict__ Wf1, const float* __restrict__ bf1,
    const float* __restrict__ Wf2, const float* __restrict__ bf2,
    const float* __restrict__ Wf3, const float* __restrict__ bf3,
    float* __restrict__ out, int n) {
  __shared__ float W1s[64 * 64];
  __shared__ float W2s[64 * 64];
  __shared__ float w3s[64];
  __shared__ float hs[8][64];
  for (int i = threadIdx.x; i < 64 * 64; i += 512) {
    W1s[i] = Wf1[i];
    W2s[i] = Wf2[i];
  }
  if (threadIdx.x < 64) w3s[threadIdx.x] = Wf3[threadIdx.x];
  const int lane = threadIdx.x & 63;
  const int w = threadIdx.x >> 6;
  const int g = lane >> 4, q = lane & 15;
  const int row = blockIdx.x * 8 + w;
  const bool valid = row < n;
  const float4* tt4 = (const float4*)tt;
  float4 acc = make_float4(0.f, 0.f, 0.f, 0.f);
  float di = 0.f;
  if (valid) {
    di = dinv[row];
    if (g == 0) acc = tt4[(size_t)row * 16 + q];
    int j = row_start[row] + g;
    const int jend = row_start[row] + cnt[row];
    for (; j + 4 < jend; j += 8) {
      int s0 = csr[j], s1 = csr[j + 4];
      float4 v0 = tt4[(size_t)s0 * 16 + q];
      float4 v1 = tt4[(size_t)s1 * 16 + q];
      acc = f4add(acc, f4add(v0, v1));
    }
    if (j < jend) acc = f4add(acc, tt4[(size_t)csr[j] * 16 + q]);
  }
  acc = f4shfl_xor_add(acc, 16);
  acc = f4shfl_xor_add(acc, 32);
  float4 b4 = ((const float4*)b2)[q];
  float4 h = make_float4(RELU(di * acc.x + b4.x), RELU(di * acc.y + b4.y),
                         RELU(di * acc.z + b4.z), RELU(di * acc.w + b4.w));
  __syncthreads();  // weights ready
  if (valid && g == 0) ((float4*)hs[w])[q] = h;
  const float4* W1s4 = (const float4*)W1s;
  const float4* W2s4 = (const float4*)W2s;
  float4 o = make_float4(0.f, 0.f, 0.f, 0.f);
  if (valid) {
#pragma unroll
    for (int i = 0; i < 16; ++i) {
      int k = g * 16 + i;
      o = f4fma(hs[w][k], W1s4[k * 16 + q], o);
    }
  }
  o = f4shfl_xor_add(o, 16);
  o = f4shfl_xor_add(o, 32);
  float4 bb = ((const float4*)bf1)[q];
  float4 h3 = make_float4(RELU(o.x + bb.x), RELU(o.y + bb.y),
                          RELU(o.z + bb.z), RELU(o.w + bb.w));
  if (valid && g == 0) ((float4*)hs[w])[q] = h3;  // wave-private, in-order
  o = make_float4(0.f, 0.f, 0.f, 0.f);
  if (valid) {
#pragma unroll
    for (int i = 0; i < 16; ++i) {
      int k = g * 16 + i;
      o = f4fma(hs[w][k], W2s4[k * 16 + q], o);
    }
  }
  o = f4shfl_xor_add(o, 16);
  o = f4shfl_xor_add(o, 32);
  bb = ((const float4*)bf2)[q];
  float4 h4 = make_float4(RELU(o.x + bb.x), RELU(o.y + bb.y),
                          RELU(o.z + bb.z), RELU(o.w + bb.w));
  // out = h4 . w3 + bf3 : every lane has full h4 for its q; reduce over q.
  float4 w3v = ((const float4*)w3s)[q];
  float p = h4.x * w3v.x + h4.y * w3v.y + h4.z * w3v.z + h4.w * w3v.w;
#pragma unroll
  for (int off = 8; off; off >>= 1) p += __shfl_xor(p, off);
  if (valid && lane == 0) out[row] = p + bf3[0];
}

extern "C" void kernel_launch(void* const* d_in, const int* in_sizes, int n_in,
                              void* d_out, int out_size, void* d_ws, size_t ws_size,
                              hipStream_t stream) {
  const float* x   = (const float*)d_in[0];
  const int*   ei  = (const int*)d_in[1];
  const float* W1  = (const float*)d_in[2];
  const float* b1  = (const float*)d_in[3];
  const float* W2  = (const float*)d_in[4];
  const float* b2  = (const float*)d_in[5];
  const float* Wf1 = (const float*)d_in[6];
  const float* bf1 = (const float*)d_in[7];
  const float* Wf2 = (const float*)d_in[8];
  const float* bf2 = (const float*)d_in[9];
  const float* Wf3 = (const float*)d_in[10];
  const float* bf3 = (const float*)d_in[11];
  float* out = (float*)d_out;

  const int n  = in_sizes[0] / 64;  // 100000
  const int ne = in_sizes[1] / 2;   // 1600000
  const int* src = ei;
  const int* dst = ei + ne;

  const size_t rowf = (size_t)n * 64;
  float* ws = (float*)d_ws;
  float* tt1  = ws;                 // [n*64]
  float* tt2  = ws + rowf;          // [n*64]
  float* dinv = ws + 2 * rowf;      // [n]
  int* ip = (int*)(dinv + n);
  int* cnt       = ip;              // [n]
  int* row_start = ip + n;          // [n]
  int* cursor    = ip + 2 * n;      // [n]
  int* bsum      = ip + 3 * n;      // [128]
  int* boff      = bsum + 128;      // [128]
  int* csr       = boff + 128;      // [ne]

  const int nb_nodes = (n + 255) / 256;
  const int nb_edges = (ne + 255) / 256;
  const int nb_rows8 = (n + 7) / 8;
  const int nblk     = (n + 1023) / 1024;

  // CSR build (by destination)
  k_zero_int<<<nb_nodes, 256, 0, stream>>>(cnt, n);
  k_hist<<<nb_edges, 256, 0, stream>>>(dst, cnt, ne);
  k_blocksum<<<nblk, 256, 0, stream>>>(cnt, bsum, n);
  k_scan_small<<<1, 64, 0, stream>>>(bsum, boff, nblk);
  k_scan_local<<<nblk, 256, 0, stream>>>(cnt, boff, row_start, cursor, n);
  k_fill<<<nb_edges, 256, 0, stream>>>(src, dst, cursor, csr, ne);
  k_dinv<<<nb_nodes, 256, 0, stream>>>(cnt, dinv, n);

  // layer 1 transform
  k_transform<<<nb_rows8, 512, 0, stream>>>(x, W1, dinv, tt1, n);
  // gather-agg 1 + epilogue + layer-2 transform
  k_mid_g<<<nb_rows8, 512, 0, stream>>>(tt1, csr, row_start, cnt, dinv, b1, W2, tt2, n);
  // gather-agg 2 + epilogue + MLP head
  k_final_g<<<nb_rows8, 512, 0, stream>>>(tt2, csr, row_start, cnt, dinv, b2,
                                          Wf1, bf1, Wf2, bf2, Wf3, bf3, out, n);
}

// Round 5
// 382.681 us; speedup vs baseline: 1.3553x; 1.3553x over previous
//
#include <hip/hip_runtime.h>

#define RELU(v) fmaxf((v), 0.0f)

constexpr int BS = 512;       // nodes per bucket
constexpr int LOG_BS = 9;
constexpr int CAP = 16384;    // record slab capacity per bucket (mean 8163)
constexpr int EPB = 8192;     // edges per partition block

__device__ __forceinline__ float4 f4add(float4 a, float4 b) {
  return make_float4(a.x + b.x, a.y + b.y, a.z + b.z, a.w + b.w);
}
__device__ __forceinline__ float4 f4fma(float s, float4 w, float4 a) {
  return make_float4(fmaf(s, w.x, a.x), fmaf(s, w.y, a.y),
                     fmaf(s, w.z, a.z), fmaf(s, w.w, a.w));
}
__device__ __forceinline__ float4 f4shfl_xor_add(float4 v, int m) {
  v.x += __shfl_xor(v.x, m);
  v.y += __shfl_xor(v.y, m);
  v.z += __shfl_xor(v.z, m);
  v.w += __shfl_xor(v.w, m);
  return v;
}

// ---------- bucketed CSR build ----------

__global__ __launch_bounds__(256) void k_initcur(int* __restrict__ gcursor, int nb) {
  int b = threadIdx.x;
  if (b < nb) gcursor[b] = b * CAP;  // slab base
}

// P1: partition edges into per-dst-range bucket slabs as packed (src<<9|dlocal)
__global__ __launch_bounds__(256) void k_part(const int* __restrict__ src,
                                              const int* __restrict__ dst, int ne,
                                              int nb, int* __restrict__ gcursor,
                                              int* __restrict__ recbuf) {
  __shared__ int hist[256];
  __shared__ int base[256];
  const int t = threadIdx.x;
  const int e0 = blockIdx.x * EPB;
  hist[t] = 0;
  __syncthreads();
  for (int i = 0; i < EPB; i += 256) {
    int e = e0 + i + t;
    if (e < ne) atomicAdd(&hist[dst[e] >> LOG_BS], 1);
  }
  __syncthreads();
  if (t < nb) base[t] = atomicAdd(&gcursor[t], hist[t]);  // reserve chunk
  __syncthreads();
  hist[t] = 0;  // reuse as local cursor
  __syncthreads();
  for (int i = 0; i < EPB; i += 256) {
    int e = e0 + i + t;
    if (e < ne) {
      int d = dst[e];
      int b = d >> LOG_BS;
      int pos = base[b] + atomicAdd(&hist[b], 1);
      if (pos < (b + 1) * CAP)  // defensive (never triggers for uniform input)
        recbuf[pos] = (src[e] << LOG_BS) | (d & (BS - 1));
    }
  }
}

// parallel scan of bucket counts -> bucket edge bases; row_start[n]=ne
__global__ __launch_bounds__(256) void k_bscan(const int* __restrict__ gcursor,
                                               int* __restrict__ bbase,
                                               int* __restrict__ row_start,
                                               int nb, int n) {
  __shared__ int tsum[256];
  const int t = threadIdx.x;
  const int v = (t < nb) ? (gcursor[t] - t * CAP) : 0;
  int x = v;
  tsum[t] = x;
  __syncthreads();
  for (int off = 1; off < 256; off <<= 1) {
    int y = (t >= off) ? tsum[t - off] : 0;
    __syncthreads();
    x += y;
    tsum[t] = x;
    __syncthreads();
  }
  if (t < nb) bbase[t] = x - v;
  if (t == nb - 1) {
    bbase[nb] = x;
    row_start[n] = x;  // == ne
  }
}

// P2: per-bucket local hist + scan -> global CSR row_start/dinv + csr fill
__global__ __launch_bounds__(512) void k_bucket(
    const int* __restrict__ recbuf, const int* __restrict__ gcursor,
    const int* __restrict__ bbase, int* __restrict__ row_start,
    float* __restrict__ dinv, int* __restrict__ csr, int n) {
  __shared__ int hist[BS];
  __shared__ int tsum[BS];
  __shared__ int cur[BS];
  const int b = blockIdx.x;
  const int t = threadIdx.x;
  const int slab0 = b * CAP;
  const int cb = gcursor[b] - slab0;  // records in this bucket
  const int ebase = bbase[b];
  hist[t] = 0;
  __syncthreads();
  for (int i = t; i < cb; i += 512)
    atomicAdd(&hist[recbuf[slab0 + i] & (BS - 1)], 1);
  __syncthreads();
  const int v = hist[t];
  int x = v;  // inclusive scan over 512 counters
  tsum[t] = x;
  __syncthreads();
  for (int off = 1; off < 512; off <<= 1) {
    int y = (t >= off) ? tsum[t - off] : 0;
    __syncthreads();
    x += y;
    tsum[t] = x;
    __syncthreads();
  }
  const int excl = x - v;
  cur[t] = excl;
  const int node = b * BS + t;
  if (node < n) {
    row_start[node] = ebase + excl;
    dinv[node] = rsqrtf((float)(v + 1));  // +1 self-loop
  }
  __syncthreads();
  for (int i = t; i < cb; i += 512) {
    int rec = recbuf[slab0 + i];
    int local = rec & (BS - 1);
    int pos = ebase + atomicAdd(&cur[local], 1);
    csr[pos] = rec >> LOG_BS;
  }
}

// ---------- dense passes ----------
// Wave layout: one ROW per wave; g = lane>>4 is a 16-wide k-slice / edge
// subgroup; q = lane&15 owns 4 channels (float4). Combine: shfl_xor 16, 32.

__global__ __launch_bounds__(512) void k_transform(
    const float* __restrict__ x, const float* __restrict__ W,
    const float* __restrict__ dinv, float* __restrict__ tt, int n) {
  __shared__ float Ws[64 * 64];
  __shared__ float xs[8][64];
  for (int i = threadIdx.x; i < 64 * 64; i += 512) Ws[i] = W[i];
  const int lane = threadIdx.x & 63;
  const int w = threadIdx.x >> 6;
  const int g = lane >> 4, q = lane & 15;
  const int row = blockIdx.x * 8 + w;
  const bool valid = row < n;
  if (valid) xs[w][lane] = x[(size_t)row * 64 + lane];
  __syncthreads();  // Ws ready (xs wave-private, in-order)
  float4 o = make_float4(0.f, 0.f, 0.f, 0.f);
  const float4* Ws4 = (const float4*)Ws;
  if (valid) {
#pragma unroll
    for (int i = 0; i < 16; ++i) {
      int k = g * 16 + i;
      o = f4fma(xs[w][k], Ws4[k * 16 + q], o);
    }
  }
  o = f4shfl_xor_add(o, 16);
  o = f4shfl_xor_add(o, 32);
  if (valid && g == 0) {
    float di = dinv[row];
    ((float4*)tt)[(size_t)row * 16 + q] =
        make_float4(o.x * di, o.y * di, o.z * di, o.w * di);
  }
}

__device__ __forceinline__ float4 gather_row(const float4* __restrict__ tt4,
                                             const int* __restrict__ csr,
                                             int jbeg, int jend, int g, int q,
                                             float4 acc) {
  int j = jbeg + g;
  for (; j + 12 < jend; j += 16) {  // 4 loads in flight per subgroup
    int s0 = csr[j], s1 = csr[j + 4], s2 = csr[j + 8], s3 = csr[j + 12];
    float4 v0 = tt4[(size_t)s0 * 16 + q];
    float4 v1 = tt4[(size_t)s1 * 16 + q];
    float4 v2 = tt4[(size_t)s2 * 16 + q];
    float4 v3 = tt4[(size_t)s3 * 16 + q];
    acc = f4add(acc, f4add(f4add(v0, v1), f4add(v2, v3)));
  }
  for (; j < jend; j += 4) acc = f4add(acc, tt4[(size_t)csr[j] * 16 + q]);
  return acc;
}

// h = relu(dinv*(tt_self + sum_in tt[src]) + b); ttout = dinv * (h @ W)
__global__ __launch_bounds__(512) void k_mid_g(
    const float* __restrict__ tt, const int* __restrict__ csr,
    const int* __restrict__ row_start, const float* __restrict__ dinv,
    const float* __restrict__ b, const float* __restrict__ W,
    float* __restrict__ ttout, int n) {
  __shared__ float Ws[64 * 64];
  __shared__ float hs[8][64];
  for (int i = threadIdx.x; i < 64 * 64; i += 512) Ws[i] = W[i];
  const int lane = threadIdx.x & 63;
  const int w = threadIdx.x >> 6;
  const int g = lane >> 4, q = lane & 15;
  const int row = blockIdx.x * 8 + w;
  const bool valid = row < n;
  const float4* tt4 = (const float4*)tt;
  float4 acc = make_float4(0.f, 0.f, 0.f, 0.f);
  float di = 0.f;
  if (valid) {
    di = dinv[row];
    if (g == 0) acc = tt4[(size_t)row * 16 + q];  // self-loop term
    acc = gather_row(tt4, csr, row_start[row], row_start[row + 1], g, q, acc);
  }
  acc = f4shfl_xor_add(acc, 16);
  acc = f4shfl_xor_add(acc, 32);
  float4 b4 = ((const float4*)b)[q];
  float4 h = make_float4(RELU(di * acc.x + b4.x), RELU(di * acc.y + b4.y),
                         RELU(di * acc.z + b4.z), RELU(di * acc.w + b4.w));
  __syncthreads();  // Ws ready
  if (valid && g == 0) ((float4*)hs[w])[q] = h;
  float4 o = make_float4(0.f, 0.f, 0.f, 0.f);
  const float4* Ws4 = (const float4*)Ws;
  if (valid) {
#pragma unroll
    for (int i = 0; i < 16; ++i) {
      int k = g * 16 + i;
      o = f4fma(hs[w][k], Ws4[k * 16 + q], o);
    }
  }
  o = f4shfl_xor_add(o, 16);
  o = f4shfl_xor_add(o, 32);
  if (valid && g == 0)
    ((float4*)ttout)[(size_t)row * 16 + q] =
        make_float4(o.x * di, o.y * di, o.z * di, o.w * di);
}

// h2 = relu(dinv*agg+b2); h3 = relu(h2@Wf1+bf1); h4 = relu(h3@Wf2+bf2);
// out = h4 . Wf3 + bf3
__global__ __launch_bounds__(512) void k_final_g(
    const float* __restrict__ tt, const int* __restrict__ csr,
    const int* __restrict__ row_start, const float* __restrict__ dinv,
    const float* __restrict__ b2,
    const float* __restrict__ Wf1, const float* __restrict__ bf1,
    const float* __restrict__ Wf2, const float* __restrict__ bf2,
    const float* __restrict__ Wf3, const float* __restrict__ bf3,
    float* __restrict__ out, int n) {
  __shared__ float W1s[64 * 64];
  __shared__ float W2s[64 * 64];
  __shared__ float w3s[64];
  __shared__ float hs[8][64];
  for (int i = threadIdx.x; i < 64 * 64; i += 512) {
    W1s[i] = Wf1[i];
    W2s[i] = Wf2[i];
  }
  if (threadIdx.x < 64) w3s[threadIdx.x] = Wf3[threadIdx.x];
  const int lane = threadIdx.x & 63;
  const int w = threadIdx.x >> 6;
  const int g = lane >> 4, q = lane & 15;
  const int row = blockIdx.x * 8 + w;
  const bool valid = row < n;
  const float4* tt4 = (const float4*)tt;
  float4 acc = make_float4(0.f, 0.f, 0.f, 0.f);
  float di = 0.f;
  if (valid) {
    di = dinv[row];
    if (g == 0) acc = tt4[(size_t)row * 16 + q];
    acc = gather_row(tt4, csr, row_start[row], row_start[row + 1], g, q, acc);
  }
  acc = f4shfl_xor_add(acc, 16);
  acc = f4shfl_xor_add(acc, 32);
  float4 b4 = ((const float4*)b2)[q];
  float4 h = make_float4(RELU(di * acc.x + b4.x), RELU(di * acc.y + b4.y),
                         RELU(di * acc.z + b4.z), RELU(di * acc.w + b4.w));
  __syncthreads();  // weights ready
  if (valid && g == 0) ((float4*)hs[w])[q] = h;
  const float4* W1s4 = (const float4*)W1s;
  const float4* W2s4 = (const float4*)W2s;
  float4 o = make_float4(0.f, 0.f, 0.f, 0.f);
  if (valid) {
#pragma unroll
    for (int i = 0; i < 16; ++i) {
      int k = g * 16 + i;
      o = f4fma(hs[w][k], W1s4[k * 16 + q], o);
    }
  }
  o = f4shfl_xor_add(o, 16);
  o = f4shfl_xor_add(o, 32);
  float4 bb = ((const float4*)bf1)[q];
  float4 h3 = make_float4(RELU(o.x + bb.x), RELU(o.y + bb.y),
                          RELU(o.z + bb.z), RELU(o.w + bb.w));
  if (valid && g == 0) ((float4*)hs[w])[q] = h3;  // wave-private
  o = make_float4(0.f, 0.f, 0.f, 0.f);
  if (valid) {
#pragma unroll
    for (int i = 0; i < 16; ++i) {
      int k = g * 16 + i;
      o = f4fma(hs[w][k], W2s4[k * 16 + q], o);
    }
  }
  o = f4shfl_xor_add(o, 16);
  o = f4shfl_xor_add(o, 32);
  bb = ((const float4*)bf2)[q];
  float4 h4 = make_float4(RELU(o.x + bb.x), RELU(o.y + bb.y),
                          RELU(o.z + bb.z), RELU(o.w + bb.w));
  float4 w3v = ((const float4*)w3s)[q];
  float p = h4.x * w3v.x + h4.y * w3v.y + h4.z * w3v.z + h4.w * w3v.w;
#pragma unroll
  for (int off = 8; off; off >>= 1) p += __shfl_xor(p, off);
  if (valid && lane == 0) out[row] = p + bf3[0];
}

extern "C" void kernel_launch(void* const* d_in, const int* in_sizes, int n_in,
                              void* d_out, int out_size, void* d_ws, size_t ws_size,
                              hipStream_t stream) {
  const float* x   = (const float*)d_in[0];
  const int*   ei  = (const int*)d_in[1];
  const float* W1  = (const float*)d_in[2];
  const float* b1  = (const float*)d_in[3];
  const float* W2  = (const float*)d_in[4];
  const float* b2  = (const float*)d_in[5];
  const float* Wf1 = (const float*)d_in[6];
  const float* bf1 = (const float*)d_in[7];
  const float* Wf2 = (const float*)d_in[8];
  const float* bf2 = (const float*)d_in[9];
  const float* Wf3 = (const float*)d_in[10];
  const float* bf3 = (const float*)d_in[11];
  float* out = (float*)d_out;

  const int n  = in_sizes[0] / 64;  // 100000
  const int ne = in_sizes[1] / 2;   // 1600000
  const int* src = ei;
  const int* dst = ei + ne;
  const int NB = (n + BS - 1) / BS;  // 196

  const size_t rowf = (size_t)n * 64;
  float* ws = (float*)d_ws;
  float* tt1  = ws;                       // [n*64]
  float* tt2  = tt1 + rowf;               // [n*64]
  float* dinv = tt2 + rowf;               // [n]
  int* row_start = (int*)(dinv + n);      // [n+1]
  int* gcursor   = row_start + (n + 1);   // [NB]
  int* bbase     = gcursor + NB;          // [NB+1]
  int* csr       = bbase + (NB + 1);      // [ne]
  // recbuf (NB*CAP ints = 12.8 MB) aliases tt2 (25.6 MB): recbuf is dead after
  // k_bucket; tt2 is first written by k_mid_g, strictly later in stream order.
  int* recbuf    = (int*)tt2;

  const int nb_part  = (ne + EPB - 1) / EPB;
  const int nb_rows8 = (n + 7) / 8;

  // CSR build (bucketed two-pass)
  k_initcur<<<1, 256, 0, stream>>>(gcursor, NB);
  k_part<<<nb_part, 256, 0, stream>>>(src, dst, ne, NB, gcursor, recbuf);
  k_bscan<<<1, 256, 0, stream>>>(gcursor, bbase, row_start, NB, n);
  k_bucket<<<NB, 512, 0, stream>>>(recbuf, gcursor, bbase, row_start, dinv, csr, n);

  // layer 1 transform
  k_transform<<<nb_rows8, 512, 0, stream>>>(x, W1, dinv, tt1, n);
  // gather-agg 1 + epilogue + layer-2 transform
  k_mid_g<<<nb_rows8, 512, 0, stream>>>(tt1, csr, row_start, dinv, b1, W2, tt2, n);
  // gather-agg 2 + epilogue + MLP head
  k_final_g<<<nb_rows8, 512, 0, stream>>>(tt2, csr, row_start, dinv, b2,
                                          Wf1, bf1, Wf2, bf2, Wf3, bf3, out, n);
}